// Round 1
// baseline (1893.164 us; speedup 1.0000x reference)
//
#include <hip/hip_runtime.h>
#include <math.h>

#define BATCH 1024
#define VOCAB 100000
#define EDIM  300
#define TOPK  10
#define NK    11      // keep top-(k+1), drop rank-1 at the end
#define RB    128     // rows per block (phase 1)
#define NT    128     // vocab tile width
#define KT    32      // k tile
#define LSTR  36      // LDS row stride in floats for Q/W tiles (pad, 16B-aligned rows)
#define SSTR  65      // sim LDS stride (64 cols + 1 pad)

template<int N>
__device__ __forceinline__ void topk_insert(float (&ts)[N], int (&ti)[N], float val, int vi) {
    if (val <= ts[N-1]) return;
    // unrolled predicated insertion; all indices compile-time -> stays in VGPRs
    #pragma unroll
    for (int p = N-1; p >= 0; --p) {
        bool gt  = val > ts[p];
        bool gtp = (p > 0) ? (val > ts[p-1]) : false;
        float ns = gt ? (gtp ? ts[p-1] : val) : ts[p];
        int   ni = gt ? (gtp ? ti[p-1] : vi)  : ti[p];
        ts[p] = ns; ti[p] = ni;
    }
}

// Phase 1: for each (row-block, vocab-chunk), compute sim tile-by-tile (fp32),
// keep per-(row, half-scan-thread) top-11 candidates, write to workspace.
__global__ __launch_bounds__(256, 2)
void sim_phase1(const int* __restrict__ wordid, const float* __restrict__ weight,
                float* __restrict__ ws_s, int* __restrict__ ws_i,
                int CH, int CV)
{
    __shared__ float Qs[RB][LSTR];
    __shared__ float Ws[NT][LSTR];
    __shared__ float Sim[RB][SSTR];
    __shared__ int   Wid[RB];

    const int t     = threadIdx.x;
    const int chunk = blockIdx.x;
    const int rb    = blockIdx.y;
    const int r0    = rb * RB;
    const int v0    = chunk * CV;

    const int tr = t >> 4;   // 0..15 (row group)
    const int tc = t & 15;   // 0..15 (col group)

    const int srow = t >> 1; // scan row 0..127
    const int ssub = t & 1;  // which 32-col half of the 64-col half-tile

    if (t < RB) Wid[t] = wordid[r0 + t];

    float ts[NK]; int ti[NK];
    #pragma unroll
    for (int i = 0; i < NK; ++i) { ts[i] = -INFINITY; ti[i] = 0; }

    const int ntile = (CV + NT - 1) / NT;

    for (int tile = 0; tile < ntile; ++tile) {
        const int vt0 = v0 + tile * NT;

        float acc[8][8];
        #pragma unroll
        for (int i = 0; i < 8; ++i)
            #pragma unroll
            for (int j = 0; j < 8; ++j) acc[i][j] = 0.f;

        for (int kt = 0; kt < EDIM; kt += KT) {
            __syncthreads(); // protect LDS from previous iteration's readers
            // load Q tile: 128 rows x 32 k = 1024 float4s, 4 per thread
            #pragma unroll
            for (int i = 0; i < 4; ++i) {
                int idx = t + 256 * i;
                int row = idx >> 3;
                int c4  = idx & 7;
                int k   = kt + c4 * 4;
                float4 val = make_float4(0.f, 0.f, 0.f, 0.f);
                if (k + 3 < EDIM) {
                    int w = Wid[row];
                    val = *reinterpret_cast<const float4*>(&weight[(size_t)w * EDIM + k]);
                }
                *reinterpret_cast<float4*>(&Qs[row][c4 * 4]) = val;
            }
            // load W tile
            #pragma unroll
            for (int i = 0; i < 4; ++i) {
                int idx = t + 256 * i;
                int row = idx >> 3;
                int c4  = idx & 7;
                int k   = kt + c4 * 4;
                int v   = vt0 + row;
                float4 val = make_float4(0.f, 0.f, 0.f, 0.f);
                if (k + 3 < EDIM && v < VOCAB) {
                    val = *reinterpret_cast<const float4*>(&weight[(size_t)v * EDIM + k]);
                }
                *reinterpret_cast<float4*>(&Ws[row][c4 * 4]) = val;
            }
            __syncthreads();
            // compute: 8x8 fp32 register tile per thread
            #pragma unroll
            for (int k4 = 0; k4 < 8; ++k4) {
                float4 q[8], w[8];
                #pragma unroll
                for (int i = 0; i < 8; ++i)
                    q[i] = *reinterpret_cast<const float4*>(&Qs[tr + 16 * i][k4 * 4]);
                #pragma unroll
                for (int j = 0; j < 8; ++j)
                    w[j] = *reinterpret_cast<const float4*>(&Ws[tc + 16 * j][k4 * 4]);
                #pragma unroll
                for (int i = 0; i < 8; ++i)
                    #pragma unroll
                    for (int j = 0; j < 8; ++j) {
                        acc[i][j] += q[i].x * w[j].x;
                        acc[i][j] += q[i].y * w[j].y;
                        acc[i][j] += q[i].z * w[j].z;
                        acc[i][j] += q[i].w * w[j].w;
                    }
            }
        }

        // top-k scan of this tile, two 64-col halves through Sim LDS
        #pragma unroll
        for (int h = 0; h < 2; ++h) {
            __syncthreads();
            #pragma unroll
            for (int i = 0; i < 8; ++i)
                #pragma unroll
                for (int jj = 0; jj < 4; ++jj) {
                    int j = h * 4 + jj;
                    Sim[tr + 16 * i][tc + 16 * jj] = acc[i][j]; // col (tc+16j) - 64h
                }
            __syncthreads();
            int cbase = tile * NT + h * 64 + ssub * 32; // chunk-local col base
            #pragma unroll
            for (int c = 0; c < 32; ++c) {
                int cl = cbase + c;
                int v  = v0 + cl;
                bool valid = (cl < CV) && (v < VOCAB);
                float val = valid ? Sim[srow][ssub * 32 + c] : -INFINITY;
                topk_insert<NK>(ts, ti, val, v);
            }
        }
    }

    // write this thread's candidates
    size_t base = (((size_t)(r0 + srow) * CH + chunk) * 2 + ssub) * NK;
    #pragma unroll
    for (int i = 0; i < NK; ++i) { ws_s[base + i] = ts[i]; ws_i[base + i] = ti[i]; }
}

// Phase 2: per row, merge CH*2 candidate lists of NK each -> top-11 sorted,
// drop rank 1, write 10 scores + 10 indices (as float).
__global__ __launch_bounds__(64)
void sim_phase2(const float* __restrict__ ws_s, const int* __restrict__ ws_i,
                float* __restrict__ out, int CH)
{
    const int row  = blockIdx.x;
    const int lane = threadIdx.x;
    const int NC   = CH * 2 * NK;

    const float* rs = ws_s + (size_t)row * CH * 2 * NK;
    const int*   ri = ws_i + (size_t)row * CH * 2 * NK;

    float ts[NK]; int ti[NK];
    #pragma unroll
    for (int i = 0; i < NK; ++i) { ts[i] = -INFINITY; ti[i] = 0; }

    for (int c = lane; c < NC; c += 64)
        topk_insert<NK>(ts, ti, rs[c], ri[c]);

    __shared__ float Ls[64 * NK];
    __shared__ int   Li[64 * NK];
    #pragma unroll
    for (int i = 0; i < NK; ++i) { Ls[lane * NK + i] = ts[i]; Li[lane * NK + i] = ti[i]; }
    __syncthreads();

    if (lane == 0) {
        float fs[NK]; int fi[NK];
        #pragma unroll
        for (int i = 0; i < NK; ++i) { fs[i] = -INFINITY; fi[i] = 0; }
        for (int c = 0; c < 64 * NK; ++c)
            topk_insert<NK>(fs, fi, Ls[c], Li[c]);
        // drop rank-1 (the query word), emit ranks 2..11
        #pragma unroll
        for (int k = 0; k < TOPK; ++k) {
            out[(size_t)row * TOPK + k] = fs[k + 1];
            out[(size_t)BATCH * TOPK + (size_t)row * TOPK + k] = (float)fi[k + 1];
        }
    }
}

extern "C" void kernel_launch(void* const* d_in, const int* in_sizes, int n_in,
                              void* d_out, int out_size, void* d_ws, size_t ws_size,
                              hipStream_t stream) {
    const int*   wordid = (const int*)d_in[0];
    const float* weight = (const float*)d_in[1];
    float* out = (float*)d_out;

    // adaptive chunk count so candidate buffers fit in ws
    const size_t per_ch = (size_t)BATCH * 2 * NK * 8; // score+idx bytes per chunk
    int CH = 100;
    while (CH > 1 && (size_t)CH * per_ch > ws_size) CH >>= 1;
    const int CV = (VOCAB + CH - 1) / CH;

    float* ws_s = (float*)d_ws;
    int*   ws_i = (int*)((char*)d_ws + (size_t)BATCH * CH * 2 * NK * sizeof(float));

    dim3 g1(CH, BATCH / RB);
    sim_phase1<<<g1, 256, 0, stream>>>(wordid, weight, ws_s, ws_i, CH, CV);
    sim_phase2<<<BATCH, 64, 0, stream>>>(ws_s, ws_i, out, CH);
}

// Round 2
// 1284.485 us; speedup vs baseline: 1.4739x; 1.4739x over previous
//
#include <hip/hip_runtime.h>
#include <math.h>

#define BATCH 1024
#define VOCAB 100000
#define KDIM  300
#define TOPK  10
#define NK2   16     // candidates kept per scanner / per row
#define RB    128    // query rows per block
#define NT    128    // vocab cols per tile
#define ASTR  328    // A LDS row stride (bf16 elems): 320 + 8 pad -> 2-way-free banks
#define BSTR  72     // B LDS row stride (bf16 elems): 64 + 8 pad
#define SSTR  33     // sim staging stride (f32)

typedef __attribute__((ext_vector_type(8))) short bf16x8;
typedef __attribute__((ext_vector_type(4))) float f32x4;

__device__ __forceinline__ ushort f2bf(float f) {
    union { float f; unsigned u; } v; v.f = f;
    unsigned r = v.u + 0x7FFFu + ((v.u >> 16) & 1u);  // RNE
    return (ushort)(r >> 16);
}

template<int N>
__device__ __forceinline__ void topk_insert(float (&ts)[N], int (&ti)[N], float val, int vi) {
    if (val <= ts[N-1]) return;
    #pragma unroll
    for (int p = N-1; p >= 0; --p) {
        bool gt  = val > ts[p];
        bool gtp = (p > 0) ? (val > ts[p-1]) : false;
        float ns = gt ? (gtp ? ts[p-1] : val) : ts[p];
        int   ni = gt ? (gtp ? ti[p-1] : vi)  : ti[p];
        ts[p] = ns; ti[p] = ni;
    }
}

#define LOADB(tile, ks) {                                                      \
    _Pragma("unroll")                                                          \
    for (int j = 0; j < 8; ++j) {                                              \
        int idx = t + 256*j;                                                   \
        int col = idx >> 4;                                                    \
        int f4  = idx & 15;                                                    \
        int cl  = (tile)*NT + col;                                             \
        int kg  = (ks)*64 + f4*4;                                              \
        rg[j] = make_float4(0.f,0.f,0.f,0.f);                                  \
        int v = v0 + cl;                                                       \
        if (cl < CV && v < VOCAB && kg < KDIM)                                 \
            rg[j] = *reinterpret_cast<const float4*>(&weight[(size_t)v*KDIM + kg]); \
    } }

#define STOREB(bufsel) {                                                       \
    _Pragma("unroll")                                                          \
    for (int j = 0; j < 8; ++j) {                                              \
        int idx = t + 256*j;                                                   \
        int col = idx >> 4;                                                    \
        int f4  = idx & 15;                                                    \
        ushort4 u;                                                             \
        u.x = f2bf(rg[j].x); u.y = f2bf(rg[j].y);                              \
        u.z = f2bf(rg[j].z); u.w = f2bf(rg[j].w);                              \
        *reinterpret_cast<ushort4*>(&Bs[bufsel][col][f4*4]) = u;               \
    } }

// Phase 1: bf16-MFMA approximate GEMM + fused per-row top-16 candidates.
__global__ __launch_bounds__(256, 1)
void sim_mfma(const int* __restrict__ wordid, const float* __restrict__ weight,
              float* __restrict__ ws_s, int* __restrict__ ws_i,
              int CH, int CV)
{
    __shared__ ushort As[RB][ASTR];
    __shared__ ushort Bs[2][NT][BSTR];
    __shared__ float  Sim[RB][SSTR];
    __shared__ int    Wid[RB];

    const int t     = threadIdx.x;
    const int chunk = blockIdx.x;
    const int r0    = blockIdx.y * RB;
    const int v0    = chunk * CV;
    const int wid   = t >> 6, lane = t & 63;
    const int wm    = wid >> 1, wn = wid & 1;
    const int l16   = lane & 15, lk = lane >> 4;
    const int srow  = t >> 1, ssub = t & 1;

    if (t < RB) Wid[t] = wordid[r0 + t];
    __syncthreads();

    // A: gather 128 query rows, convert to bf16, K padded to 320 with zeros.
    #pragma unroll 4
    for (int i = 0; i < 40; ++i) {
        int idx = t + 256*i;           // 0..10239 over 128 rows x 80 float4 slots
        int row = idx / 80;
        int f4  = idx - row*80;
        float4 val = make_float4(0.f,0.f,0.f,0.f);
        if (f4 < 75)
            val = *reinterpret_cast<const float4*>(&weight[(size_t)Wid[row]*KDIM + f4*4]);
        ushort4 u;
        u.x = f2bf(val.x); u.y = f2bf(val.y); u.z = f2bf(val.z); u.w = f2bf(val.w);
        *reinterpret_cast<ushort4*>(&As[row][f4*4]) = u;
    }

    float ts[NK2]; int ti[NK2];
    #pragma unroll
    for (int i = 0; i < NK2; ++i) { ts[i] = -INFINITY; ti[i] = 0; }

    const int ntile = (CV + NT - 1) / NT;
    float4 rg[8];

    LOADB(0, 0);   // prologue

    for (int tile = 0; tile < ntile; ++tile) {
        f32x4 acc[4][4] = {};

        for (int ks = 0; ks < 5; ++ks) {
            STOREB(ks & 1);
            __syncthreads();                       // B tile visible to all
            if (ks < 4)               { LOADB(tile, ks+1); }      // overlap next stage
            else if (tile+1 < ntile)  { LOADB(tile+1, 0); }       // next tile prologue
            #pragma unroll
            for (int kk = 0; kk < 2; ++kk) {
                bf16x8 af[4], bfr[4];
                int ka = ks*64 + kk*32 + lk*8;     // k in padded A
                int kb = kk*32 + lk*8;             // k local to B tile
                #pragma unroll
                for (int m = 0; m < 4; ++m)
                    af[m] = *reinterpret_cast<const bf16x8*>(&As[wm*64 + m*16 + l16][ka]);
                #pragma unroll
                for (int n = 0; n < 4; ++n)
                    bfr[n] = *reinterpret_cast<const bf16x8*>(&Bs[ks & 1][wn*64 + n*16 + l16][kb]);
                #pragma unroll
                for (int m = 0; m < 4; ++m)
                    #pragma unroll
                    for (int n = 0; n < 4; ++n)
                        acc[m][n] = __builtin_amdgcn_mfma_f32_16x16x32_bf16(af[m], bfr[n], acc[m][n], 0, 0, 0);
            }
        }

        // scan sims: stage 32 cols (one nf of both wn halves) at a time
        #pragma unroll
        for (int nf = 0; nf < 4; ++nf) {
            #pragma unroll
            for (int m = 0; m < 4; ++m)
                #pragma unroll
                for (int j = 0; j < 4; ++j)
                    Sim[wm*64 + m*16 + lk*4 + j][wn*16 + l16] = acc[m][nf][j];
            __syncthreads();
            int cb = tile*NT + ssub*64 + nf*16;
            #pragma unroll
            for (int c = 0; c < 16; ++c) {
                int cl = cb + c;
                int v  = v0 + cl;
                float val = (cl < CV && v < VOCAB) ? Sim[srow][ssub*16 + c] : -INFINITY;
                topk_insert<NK2>(ts, ti, val, v);
            }
            __syncthreads();
        }
    }

    size_t base = ((((size_t)(r0 + srow))*CH + chunk)*2 + ssub)*NK2;
    #pragma unroll
    for (int i = 0; i < NK2; ++i) { ws_s[base + i] = ts[i]; ws_i[base + i] = ti[i]; }
}

// Phase 2: merge candidate lists -> approx top-16, exact fp64 rescore,
// top-11 with numpy tie-break (lower index first), drop rank-1.
__global__ __launch_bounds__(64, 4)
void merge_rescore(const float* __restrict__ ws_s, const int* __restrict__ ws_i,
                   const int* __restrict__ wordid, const float* __restrict__ weight,
                   float* __restrict__ out, int CH)
{
    __shared__ float  Ls[64*NK2];
    __shared__ int    Li[64*NK2];
    __shared__ float  CsS[NK2];
    __shared__ int    CiS[NK2];
    __shared__ double RsS[NK2];

    const int row  = blockIdx.x;
    const int lane = threadIdx.x;
    const int lists = CH * 2;

    if (lane < lists) {
        size_t base = ((size_t)row*lists + lane)*NK2;
        #pragma unroll
        for (int i = 0; i < NK2; ++i) {
            Ls[lane*NK2 + i] = ws_s[base + i];
            Li[lane*NK2 + i] = ws_i[base + i];
        }
    }
    __syncthreads();

    if (lane == 0) {
        float fs[NK2]; int fi[NK2];
        #pragma unroll
        for (int i = 0; i < NK2; ++i) { fs[i] = -INFINITY; fi[i] = 0; }
        for (int l = 0; l < lists; ++l) {
            for (int i = 0; i < NK2; ++i) {       // lists sorted desc -> early break
                float v = Ls[l*NK2 + i];
                if (v <= fs[NK2-1]) break;
                topk_insert<NK2>(fs, fi, v, Li[l*NK2 + i]);
            }
        }
        #pragma unroll
        for (int i = 0; i < NK2; ++i) { CsS[i] = fs[i]; CiS[i] = fi[i]; }
    }
    __syncthreads();

    if (lane < NK2) {
        int v = CiS[lane];
        const float4* q4 = reinterpret_cast<const float4*>(weight + (size_t)wordid[row]*KDIM);
        const float4* w4 = reinterpret_cast<const float4*>(weight + (size_t)v*KDIM);
        double a0=0, a1=0, a2=0, a3=0;
        #pragma unroll 5
        for (int i = 0; i < 75; ++i) {
            float4 a = q4[i], b = w4[i];
            a0 += (double)a.x * b.x; a1 += (double)a.y * b.y;
            a2 += (double)a.z * b.z; a3 += (double)a.w * b.w;
        }
        RsS[lane] = (a0 + a1) + (a2 + a3);
    }
    __syncthreads();

    if (lane == 0) {
        unsigned used = 0;
        for (int kk = 0; kk < TOPK + 1; ++kk) {
            int best = -1; double bs = -1e300; int bi = 0x7fffffff;
            for (int i = 0; i < NK2; ++i) {
                if ((used >> i) & 1u) continue;
                double s = RsS[i]; int vv = CiS[i];
                if (s > bs || (s == bs && vv < bi)) { best = i; bs = s; bi = vv; }
            }
            used |= 1u << best;
            if (kk >= 1) {
                out[(size_t)row*TOPK + (kk-1)] = (float)bs;
                out[(size_t)BATCH*TOPK + (size_t)row*TOPK + (kk-1)] = (float)bi;
            }
        }
    }
}

extern "C" void kernel_launch(void* const* d_in, const int* in_sizes, int n_in,
                              void* d_out, int out_size, void* d_ws, size_t ws_size,
                              hipStream_t stream) {
    const int*   wordid = (const int*)d_in[0];
    const float* weight = (const float*)d_in[1];
    float* out = (float*)d_out;

    // candidate buffer: BATCH * CH*2 * NK2 * (float + int)
    int CH = 32;                                   // 100000/CH must be exact: 32/16/8 all divide
    while (CH > 4 && (size_t)BATCH * CH * 2 * NK2 * 8 > ws_size) CH >>= 1;
    const int CV = VOCAB / CH;

    float* ws_s = (float*)d_ws;
    int*   ws_i = (int*)((char*)d_ws + (size_t)BATCH * CH * 2 * NK2 * sizeof(float));

    dim3 g1(CH, BATCH / RB);
    sim_mfma<<<g1, 256, 0, stream>>>(wordid, weight, ws_s, ws_i, CH, CV);
    merge_rescore<<<BATCH, 64, 0, stream>>>(ws_s, ws_i, wordid, weight, out, CH);
}

// Round 4
// 674.768 us; speedup vs baseline: 2.8057x; 1.9036x over previous
//
#include <hip/hip_runtime.h>
#include <math.h>

#define BATCH 1024
#define VOCAB 100000
#define KDIM  300
#define TOPK  10

#define NKB     10        // K blocks of 32 (K padded 300 -> 320)
#define NCB_B   6272      // padded vocab col-blocks of 16 (98 chunks * 64)
#define NCB_A   64        // 1024 rows / 16
#define NCHUNK  98        // col chunks of 1024
#define ITERS   4         // 256 cols per iteration
#define NKCAND  8         // per-(row,window) candidates
#define NK2     16        // final rescore set
#define NLIST   (NCHUNK*2)
#define NCAND   (NLIST*NKCAND)   // 1568 per row

typedef __attribute__((ext_vector_type(8))) short bf16x8;
typedef __attribute__((ext_vector_type(4))) float f32x4;

__device__ __forceinline__ ushort f2bf(float f) {
    union { float f; unsigned u; } v; v.f = f;
    unsigned r = v.u + 0x7FFFu + ((v.u >> 16) & 1u);  // RNE
    return (ushort)(r >> 16);
}

template<int N>
__device__ __forceinline__ void topk_insert(float (&ts)[N], int (&ti)[N], float val, int vi) {
    if (val <= ts[N-1]) return;
    #pragma unroll
    for (int p = N-1; p >= 0; --p) {
        bool gt  = val > ts[p];
        bool gtp = (p > 0) ? (val > ts[p-1]) : false;
        float ns = gt ? (gtp ? ts[p-1] : val) : ts[p];
        int   ni = gt ? (gtp ? ti[p-1] : vi)  : ti[p];
        ts[p] = ns; ti[p] = ni;
    }
}

// ---------------------------------------------------------------------------
// Kernel 1: pack weight (and gathered query rows) into bf16 MFMA fragments.
// Fragment layout per (colblock16, kb): [lane][8 bf16] where
//   row/col = base + (lane&15), k = kb*32 + (lane>>4)*8 + j   (verified in r2)
// Raw stride 324 floats (>=320, 16B-aligned rows); k=300..319 zero-filled.
// ---------------------------------------------------------------------------
__global__ __launch_bounds__(256)
void convert_frags(const int* __restrict__ wordid, const float* __restrict__ weight,
                   ushort* __restrict__ ws_b, ushort* __restrict__ ws_a, int nb_blocks)
{
    __shared__ float Raw[16][324];
    __shared__ int   Rows[16];

    const int bid = blockIdx.x;
    const int t   = threadIdx.x;
    const bool is_a = (bid >= nb_blocks);
    const int cb  = is_a ? (bid - nb_blocks) : bid;

    if (t < 16) {
        int gr = is_a ? wordid[cb*16 + t] : (cb*16 + t);
        Rows[t] = (gr < VOCAB) ? gr : -1;
    }
    __syncthreads();

    // 16 rows x 80 float4 slots (=320 floats); slots 75..79 are the zero pad
    for (int idx = t; idx < 16*80; idx += 256) {
        int row = idx / 80;
        int f4  = idx - row*80;
        int gr  = Rows[row];
        float4 v = make_float4(0.f,0.f,0.f,0.f);
        if (gr >= 0 && f4 < 75)
            v = *reinterpret_cast<const float4*>(&weight[(size_t)gr*KDIM + f4*4]);
        *reinterpret_cast<float4*>(&Raw[row][f4*4]) = v;
    }
    __syncthreads();

    ushort* dst = is_a ? ws_a : ws_b;
    for (int idx = t; idx < NKB*64; idx += 256) {
        int kb   = idx >> 6;
        int lane = idx & 63;
        int r16  = lane & 15;
        int k0   = kb*32 + (lane>>4)*8;
        unsigned p[4];
        #pragma unroll
        for (int q = 0; q < 4; ++q) {
            unsigned lo = f2bf(Raw[r16][k0 + 2*q]);
            unsigned hi = f2bf(Raw[r16][k0 + 2*q + 1]);
            p[q] = lo | (hi << 16);
        }
        *reinterpret_cast<uint4*>(&dst[((size_t)(cb*NKB + kb)*64 + lane)*8]) =
            make_uint4(p[0], p[1], p[2], p[3]);
    }
}

// ---------------------------------------------------------------------------
// Kernel 2: barrier-free MFMA GEMM + fused per-row top-8 per 512-col window.
// Block: 256 thr = 4 waves (wm in {0,1}, wn in {0,1}); wave tile 64r x 128c.
// A/B frags load global->reg directly; scan uses wave-private LDS transpose.
// ---------------------------------------------------------------------------
__global__ __launch_bounds__(256, 2)
void sim_gemm(const float* __restrict__ weight, const ushort* __restrict__ ws_b,
              const ushort* __restrict__ ws_a,
              float* __restrict__ ws_cs, int* __restrict__ ws_ci, int bmode)
{
    __shared__ float Simc[4][64][68];   // [wave][col in group][row + pad]

    const int t     = threadIdx.x;
    const int wid   = t >> 6, lane = t & 63;
    const int wm    = wid >> 1, wn = wid & 1;
    const int l16   = lane & 15, lk = lane >> 4;
    const int chunk = blockIdx.x;      // 0..97
    const int rb    = blockIdx.y;      // 0..7

    float ts[NKCAND]; int ti[NKCAND];
    #pragma unroll
    for (int i = 0; i < NKCAND; ++i) { ts[i] = -INFINITY; ti[i] = 0; }

    const int arb_base = rb*8 + wm*4;  // rowblock16 base for this wave

    for (int it = 0; it < ITERS; ++it) {
        const int cb0 = chunk*64 + it*16 + wn*8;   // col-block base (16-wide units)
        f32x4 acc[4][8] = {};

        #pragma unroll 2
        for (int kb = 0; kb < NKB; ++kb) {
            bf16x8 af[4], bf[8];
            #pragma unroll
            for (int m = 0; m < 4; ++m)
                af[m] = *reinterpret_cast<const bf16x8*>(
                    &ws_a[((size_t)((arb_base + m)*NKB + kb)*64 + lane)*8]);
            if (bmode == 0) {
                #pragma unroll
                for (int n = 0; n < 8; ++n)
                    bf[n] = *reinterpret_cast<const bf16x8*>(
                        &ws_b[((size_t)((cb0 + n)*NKB + kb)*64 + lane)*8]);
            } else {
                // fallback: build B frag from fp32 weight in-register
                #pragma unroll
                for (int n = 0; n < 8; ++n) {
                    int col = (cb0 + n)*16 + l16;
                    int k0  = kb*32 + lk*8;
                    float4 a = make_float4(0.f,0.f,0.f,0.f);
                    float4 b = make_float4(0.f,0.f,0.f,0.f);
                    if (col < VOCAB) {
                        if (k0 + 3 < KDIM)
                            a = *reinterpret_cast<const float4*>(&weight[(size_t)col*KDIM + k0]);
                        if (k0 + 7 < KDIM)
                            b = *reinterpret_cast<const float4*>(&weight[(size_t)col*KDIM + k0 + 4]);
                    }
                    uint4 w;
                    w.x = (unsigned)f2bf(a.x) | ((unsigned)f2bf(a.y) << 16);
                    w.y = (unsigned)f2bf(a.z) | ((unsigned)f2bf(a.w) << 16);
                    w.z = (unsigned)f2bf(b.x) | ((unsigned)f2bf(b.y) << 16);
                    w.w = (unsigned)f2bf(b.z) | ((unsigned)f2bf(b.w) << 16);
                    bf[n] = *reinterpret_cast<bf16x8*>(&w);
                }
            }
            #pragma unroll
            for (int m = 0; m < 4; ++m)
                #pragma unroll
                for (int n = 0; n < 8; ++n)
                    acc[m][n] = __builtin_amdgcn_mfma_f32_16x16x32_bf16(af[m], bf[n], acc[m][n], 0, 0, 0);
        }

        // scan: two groups of 4 n-frags (64 cols each), wave-private LDS
        #pragma unroll
        for (int g = 0; g < 2; ++g) {
            #pragma unroll
            for (int n = 0; n < 4; ++n)
                #pragma unroll
                for (int m = 0; m < 4; ++m)
                    *reinterpret_cast<f32x4*>(&Simc[wid][n*16 + l16][m*16 + lk*4]) = acc[m][g*4 + n];
            asm volatile("s_waitcnt lgkmcnt(0)" ::: "memory");
            __builtin_amdgcn_sched_barrier(0);
            const int colbase = chunk*1024 + it*256 + wn*128 + g*64;
            #pragma unroll
            for (int c = 0; c < 64; ++c) {
                int col = colbase + c;
                float v = (col < VOCAB) ? Simc[wid][c][lane] : -INFINITY;
                topk_insert<NKCAND>(ts, ti, v, col);
            }
            __builtin_amdgcn_sched_barrier(0);
        }
    }

    const int row = rb*128 + wm*64 + lane;
    size_t base = (((size_t)row*NCHUNK + chunk)*2 + wn)*NKCAND;
    #pragma unroll
    for (int i = 0; i < NKCAND; ++i) { ws_cs[base + i] = ts[i]; ws_ci[base + i] = ti[i]; }
}

// ---------------------------------------------------------------------------
// Kernel 3: merge 196 sorted 8-lists per row -> approx top-16, exact fp64
// rescore, top-11 with numpy tie-break (lower index first), drop rank-1.
// ---------------------------------------------------------------------------
__global__ __launch_bounds__(64, 4)
void merge_rescore(const float* __restrict__ ws_cs, const int* __restrict__ ws_ci,
                   const int* __restrict__ wordid, const float* __restrict__ weight,
                   float* __restrict__ out)
{
    __shared__ float  Ls[64*NK2];
    __shared__ int    Li[64*NK2];
    __shared__ float  CsS[NK2];
    __shared__ int    CiS[NK2];
    __shared__ double RsS[NK2];

    const int row  = blockIdx.x;
    const int lane = threadIdx.x;

    float fs[NK2]; int fi[NK2];
    #pragma unroll
    for (int i = 0; i < NK2; ++i) { fs[i] = -INFINITY; fi[i] = 0; }

    const float* rs = ws_cs + (size_t)row*NCAND;
    const int*   ri = ws_ci + (size_t)row*NCAND;
    for (int c = lane; c < NCAND; c += 64)
        topk_insert<NK2>(fs, fi, rs[c], ri[c]);

    #pragma unroll
    for (int i = 0; i < NK2; ++i) { Ls[lane*NK2 + i] = fs[i]; Li[lane*NK2 + i] = fi[i]; }
    __syncthreads();

    if (lane == 0) {
        float gs[NK2]; int gi[NK2];
        #pragma unroll
        for (int i = 0; i < NK2; ++i) { gs[i] = -INFINITY; gi[i] = 0; }
        for (int l = 0; l < 64; ++l) {
            for (int i = 0; i < NK2; ++i) {       // lane lists sorted desc
                float v = Ls[l*NK2 + i];
                if (v <= gs[NK2-1]) break;
                topk_insert<NK2>(gs, gi, v, Li[l*NK2 + i]);
            }
        }
        #pragma unroll
        for (int i = 0; i < NK2; ++i) { CsS[i] = gs[i]; CiS[i] = gi[i]; }
    }
    __syncthreads();

    if (lane < NK2) {
        int v = CiS[lane];
        const float4* q4 = reinterpret_cast<const float4*>(weight + (size_t)wordid[row]*KDIM);
        const float4* w4 = reinterpret_cast<const float4*>(weight + (size_t)v*KDIM);
        double a0=0, a1=0, a2=0, a3=0;
        #pragma unroll 5
        for (int i = 0; i < 75; ++i) {
            float4 a = q4[i], b = w4[i];
            a0 += (double)a.x * b.x; a1 += (double)a.y * b.y;
            a2 += (double)a.z * b.z; a3 += (double)a.w * b.w;
        }
        RsS[lane] = (a0 + a1) + (a2 + a3);
    }
    __syncthreads();

    if (lane == 0) {
        unsigned used = 0;
        for (int kk = 0; kk < TOPK + 1; ++kk) {
            int best = -1; double bs = -1e300; int bi = 0x7fffffff;
            for (int i = 0; i < NK2; ++i) {
                if ((used >> i) & 1u) continue;
                double s = RsS[i]; int vv = CiS[i];
                if (s > bs || (s == bs && vv < bi)) { best = i; bs = s; bi = vv; }
            }
            used |= 1u << best;
            if (kk >= 1) {
                out[(size_t)row*TOPK + (kk-1)] = (float)bs;
                out[(size_t)BATCH*TOPK + (size_t)row*TOPK + (kk-1)] = (float)bi;
            }
        }
    }
}

extern "C" void kernel_launch(void* const* d_in, const int* in_sizes, int n_in,
                              void* d_out, int out_size, void* d_ws, size_t ws_size,
                              hipStream_t stream) {
    const int*   wordid = (const int*)d_in[0];
    const float* weight = (const float*)d_in[1];
    float* out = (float*)d_out;

    const size_t SZ_B  = (size_t)NCB_B * NKB * 64 * 16;   // 64,225,280 B
    const size_t SZ_A  = (size_t)NCB_A * NKB * 64 * 16;   //    655,360 B
    const size_t SZ_CS = (size_t)BATCH * NCAND * 4;       //  6,422,528 B
    const size_t need_fast = SZ_B + SZ_A + 2*SZ_CS;

    char* p = (char*)d_ws;
    int bmode; ushort* ws_b;
    if (ws_size >= need_fast) { bmode = 0; ws_b = (ushort*)p; p += SZ_B; }
    else                      { bmode = 1; ws_b = nullptr; }
    ushort* ws_a  = (ushort*)p; p += SZ_A;
    float*  ws_cs = (float*)p;  p += SZ_CS;
    int*    ws_ci = (int*)p;

    const int nb = (bmode == 0) ? NCB_B : 0;
    convert_frags<<<nb + NCB_A, 256, 0, stream>>>(wordid, weight, ws_b, ws_a, nb);
    sim_gemm<<<dim3(NCHUNK, 8), 256, 0, stream>>>(weight, ws_b, ws_a, ws_cs, ws_ci, bmode);
    merge_rescore<<<BATCH, 64, 0, stream>>>(ws_cs, ws_ci, wordid, weight, out);
}

// Round 5
// 311.345 us; speedup vs baseline: 6.0806x; 2.1673x over previous
//
#include <hip/hip_runtime.h>
#include <math.h>

#define BATCH 1024
#define VOCAB 100000
#define KDIM  300
#define TOPK  10

#define NKB    10            // K blocks of 32 (K padded 300 -> 320)
#define NCB_B  6272          // vocab col-blocks of 16 (98 chunks * 64), pad to 100352
#define NCB_A  64            // 1024 rows / 16
#define NCHUNK 98            // col chunks of 1024
#define NWIN   8             // 128-col windows per chunk
#define CSLOT  32            // candidate u32s per (row, chunk): 2 wn * 4 lk * 4 deep
#define NCAND  (NCHUNK*CSLOT) // 3136 per row
#define NKF    24            // final exact-rescore set

typedef __attribute__((ext_vector_type(8))) short bf16x8;
typedef __attribute__((ext_vector_type(4))) float f32x4;

#define GL2LDS(gsrc, ldst)                                                    \
    __builtin_amdgcn_global_load_lds(                                         \
        (const __attribute__((address_space(1))) void*)(gsrc),                \
        (__attribute__((address_space(3))) void*)(ldst), 16, 0, 0)

__device__ __forceinline__ ushort f2bf(float f) {
    union { float f; unsigned u; } v; v.f = f;
    unsigned r = v.u + 0x7FFFu + ((v.u >> 16) & 1u);  // RNE
    return (ushort)(r >> 16);
}

// depth-4 descending insert of packed u32 (register-only, all static)
__device__ __forceinline__ void ins4(unsigned (&l)[4], unsigned e) {
    if (e <= l[3]) return;
    bool g0 = e > l[0], g1 = e > l[1], g2 = e > l[2];
    l[3] = g2 ? l[2] : e;
    l[2] = g2 ? (g1 ? l[1] : e) : l[2];
    l[1] = g1 ? (g0 ? l[0] : e) : l[1];
    l[0] = g0 ? e : l[0];
}

// descending (key,val) insert, depth N, fully unrolled
template<int N>
__device__ __forceinline__ void pins(unsigned (&ks)[N], int (&vs)[N], unsigned k, int v) {
    if (k <= ks[N-1]) return;
    #pragma unroll
    for (int p = N-1; p >= 0; --p) {
        bool gt  = k > ks[p];
        bool gtp = (p > 0) ? (k > ks[p-1]) : false;
        unsigned nk = gt ? (gtp ? ks[p-1] : k) : ks[p];
        int      nv = gt ? (gtp ? vs[p-1] : v) : vs[p];
        ks[p] = nk; vs[p] = nv;
    }
}

// ---------------------------------------------------------------------------
// Kernel 1: pack weight (and gathered query rows) into bf16 MFMA fragments,
// kb-OUTER layout so per-kb panels are contiguous:
//   B frag (kb, cb):   ws_b[((kb*NCB_B + cb)*64 + lane)*8 .. +7]
//   A frag (kb, rb16): ws_a[((kb*64   + rb16)*64 + lane)*8 .. +7]
// Fragment: elem (idx16 = lane&15, k = kb*32 + (lane>>4)*8 + j)  [r2-verified]
// ---------------------------------------------------------------------------
__global__ __launch_bounds__(256)
void convert_frags(const int* __restrict__ wordid, const float* __restrict__ weight,
                   ushort* __restrict__ ws_b, ushort* __restrict__ ws_a, int nb_blocks)
{
    __shared__ float Raw[16][324];
    __shared__ int   Rows[16];

    const int bid = blockIdx.x;
    const int t   = threadIdx.x;
    const bool is_a = (bid >= nb_blocks);
    const int cb  = is_a ? (bid - nb_blocks) : bid;

    if (t < 16) {
        int gr = is_a ? wordid[cb*16 + t] : (cb*16 + t);
        Rows[t] = (gr < VOCAB) ? gr : -1;
    }
    __syncthreads();

    // 16 rows x 80 float4 slots (=320 floats); slots 75..79 zero pad
    for (int idx = t; idx < 16*80; idx += 256) {
        int row = idx / 80;
        int f4  = idx - row*80;
        int gr  = Rows[row];
        float4 v = make_float4(0.f,0.f,0.f,0.f);
        if (gr >= 0 && f4 < 75)
            v = *reinterpret_cast<const float4*>(&weight[(size_t)gr*KDIM + f4*4]);
        *reinterpret_cast<float4*>(&Raw[row][f4*4]) = v;
    }
    __syncthreads();

    ushort* dst = is_a ? ws_a : ws_b;
    const int kstride = is_a ? 64 : NCB_B;
    for (int idx = t; idx < NKB*64; idx += 256) {
        int kb   = idx >> 6;
        int lane = idx & 63;
        int r16  = lane & 15;
        int k0   = kb*32 + (lane>>4)*8;
        unsigned p[4];
        #pragma unroll
        for (int q = 0; q < 4; ++q) {
            unsigned lo = f2bf(Raw[r16][k0 + 2*q]);
            unsigned hi = f2bf(Raw[r16][k0 + 2*q + 1]);
            p[q] = lo | (hi << 16);
        }
        *reinterpret_cast<uint4*>(&dst[((size_t)kb*kstride + cb)*512 + (size_t)lane*8]) =
            make_uint4(p[0], p[1], p[2], p[3]);
    }
}

// ---------------------------------------------------------------------------
// Kernel 2: 2-phase LDS-pipelined MFMA GEMM (swapped operands) + in-register
// per-row top-4 candidate lists, packed u32 (mono-bf16 score | col10).
// Block: 256 thr / 4 waves (wm,wn in 2x2); block tile 128 rows x 128 cols;
// chunk = 1024 cols via 8 windows. acc[m][n][r]: row = wm*64+m*16+l16,
// col = win*128 + wn*64 + n*16 + lk*4 + r.
// ---------------------------------------------------------------------------
__global__ __launch_bounds__(256, 2)
void sim_gemm(const ushort* __restrict__ ws_a, const ushort* __restrict__ ws_b,
              unsigned* __restrict__ cand)
{
    __shared__ __align__(16) ushort Abuf[2][8*512];   // 8 frags x 1 KB, double-buffered
    __shared__ __align__(16) ushort Bbuf[2][8*512];

    const int t     = threadIdx.x;
    const int wid   = t >> 6, lane = t & 63;
    const int wm    = wid >> 1, wn = wid & 1;
    const int l16   = lane & 15, lk = lane >> 4;
    const int chunk = blockIdx.x;        // 0..97
    const int rb16b = blockIdx.y * 8;    // rowblock16 base of this block

    unsigned ps[4][4];
    #pragma unroll
    for (int m = 0; m < 4; ++m)
        #pragma unroll
        for (int e = 0; e < 4; ++e) ps[m][e] = 0u;

    // stage (it2, kb2) into buffer s: 16 x 1KB issues, 4 per wave
    auto stage = [&](int it2, int kb2, int s) {
        const int f = wid * 2;
        const ushort* asrc = ws_a + ((size_t)kb2*64 + rb16b + f)*512 + (size_t)lane*8;
        GL2LDS(asrc,       &Abuf[s][f*512]);
        GL2LDS(asrc + 512, &Abuf[s][(f+1)*512]);
        const ushort* bsrc = ws_b + ((size_t)kb2*NCB_B + chunk*64 + it2*8 + f)*512 + (size_t)lane*8;
        GL2LDS(bsrc,       &Bbuf[s][f*512]);
        GL2LDS(bsrc + 512, &Bbuf[s][(f+1)*512]);
    };

    stage(0, 0, 0);
    __syncthreads();                      // drains vmcnt(0) before barrier
    int cur = 0;

    for (int it = 0; it < NWIN; ++it) {
        f32x4 acc[4][4] = {};

        for (int kb = 0; kb < NKB; ++kb) {
            // prefetch next K-step (or next window's first) into other buffer
            if (kb < NKB-1)      stage(it, kb+1, cur ^ 1);
            else if (it < NWIN-1) stage(it+1, 0, cur ^ 1);

            bf16x8 af[4], bfr[4];
            #pragma unroll
            for (int m = 0; m < 4; ++m)
                af[m] = *reinterpret_cast<const bf16x8*>(&Abuf[cur][(wm*4+m)*512 + lane*8]);
            #pragma unroll
            for (int n = 0; n < 4; ++n)
                bfr[n] = *reinterpret_cast<const bf16x8*>(&Bbuf[cur][(wn*4+n)*512 + lane*8]);

            #pragma unroll
            for (int m = 0; m < 4; ++m)
                #pragma unroll
                for (int n = 0; n < 4; ++n)
                    acc[m][n] = __builtin_amdgcn_mfma_f32_16x16x32_bf16(bfr[n], af[m], acc[m][n], 0, 0, 0);

            if (kb == NKB-1) {
                // register scan: pack + insert while next stage is in flight
                #pragma unroll
                for (int m = 0; m < 4; ++m)
                    #pragma unroll
                    for (int n = 0; n < 4; ++n)
                        #pragma unroll
                        for (int r = 0; r < 4; ++r) {
                            union { float f; unsigned u; } cv; cv.f = acc[m][n][r];
                            unsigned b = cv.u >> 16;                      // trunc bf16 (monotone buckets)
                            unsigned mono = (b & 0x8000u) ? (b ^ 0xFFFFu) : (b | 0x8000u);
                            unsigned col10 = (unsigned)(it*128 + wn*64 + n*16 + lk*4 + r);
                            ins4(ps[m], (mono << 16) | col10);
                        }
            }
            __syncthreads();              // vmcnt(0)+lgkmcnt(0)+barrier (2-phase step)
            cur ^= 1;
        }
    }

    // writeout: cand[row][chunk][wn][lk][4] as uint4
    const int r0 = blockIdx.y * 128;
    #pragma unroll
    for (int m = 0; m < 4; ++m) {
        int row = r0 + wm*64 + m*16 + l16;
        size_t base = (size_t)row*NCAND + chunk*CSLOT + wn*16 + lk*4;
        *reinterpret_cast<uint4*>(&cand[base]) =
            make_uint4(ps[m][0], ps[m][1], ps[m][2], ps[m][3]);
    }
}

// ---------------------------------------------------------------------------
// Kernel 3: per row, merge 3136 packed candidates -> top-24 by approx key,
// exact fp64 rescore, top-11 with numpy tie-break (lower index), drop rank-1.
// ---------------------------------------------------------------------------
__global__ __launch_bounds__(64, 4)
void merge_rescore(const unsigned* __restrict__ cand, const int* __restrict__ wordid,
                   const float* __restrict__ weight, float* __restrict__ out)
{
    __shared__ unsigned Ks[64*16];
    __shared__ int      Vs[64*16];
    __shared__ int      Fv[NKF];
    __shared__ double   Rs[NKF];

    const int row  = blockIdx.x;
    const int lane = threadIdx.x;

    unsigned ks[16]; int vs[16];
    #pragma unroll
    for (int i = 0; i < 16; ++i) { ks[i] = 0u; vs[i] = 0; }

    const unsigned* rc = cand + (size_t)row*NCAND;
    for (int c = lane; c < NCAND; c += 64) {
        unsigned e = rc[c];
        int col = ((c >> 5) << 10) | (int)(e & 1023u);   // chunk*1024 + col10
        pins<16>(ks, vs, e, col);
    }
    #pragma unroll
    for (int i = 0; i < 16; ++i) { Ks[lane*16 + i] = ks[i]; Vs[lane*16 + i] = vs[i]; }
    __syncthreads();

    if (lane == 0) {
        unsigned gk[NKF]; int gv[NKF];
        #pragma unroll
        for (int i = 0; i < NKF; ++i) { gk[i] = 0u; gv[i] = 0; }
        for (int l = 0; l < 64; ++l) {
            for (int i = 0; i < 16; ++i) {            // lane lists sorted desc
                unsigned e = Ks[l*16 + i];
                if (e <= gk[NKF-1]) break;
                pins<NKF>(gk, gv, e, Vs[l*16 + i]);
            }
        }
        #pragma unroll
        for (int i = 0; i < NKF; ++i) Fv[i] = gv[i];
    }
    __syncthreads();

    if (lane < NKF) {
        int v = Fv[lane];
        const float4* q4 = reinterpret_cast<const float4*>(weight + (size_t)wordid[row]*KDIM);
        const float4* w4 = reinterpret_cast<const float4*>(weight + (size_t)v*KDIM);
        double a0=0, a1=0, a2=0, a3=0;
        #pragma unroll 5
        for (int i = 0; i < 75; ++i) {
            float4 a = q4[i], b = w4[i];
            a0 += (double)a.x * b.x; a1 += (double)a.y * b.y;
            a2 += (double)a.z * b.z; a3 += (double)a.w * b.w;
        }
        Rs[lane] = (a0 + a1) + (a2 + a3);
    }
    __syncthreads();

    if (lane == 0) {
        unsigned used = 0;
        for (int kk = 0; kk < TOPK + 1; ++kk) {
            int best = -1; double bs = -1e300; int bi = 0x7fffffff;
            for (int i = 0; i < NKF; ++i) {
                if ((used >> i) & 1u) continue;
                double s = Rs[i]; int vv = Fv[i];
                if (s > bs || (s == bs && vv < bi)) { best = i; bs = s; bi = vv; }
            }
            used |= 1u << best;
            if (kk >= 1) {
                out[(size_t)row*TOPK + (kk-1)] = (float)bs;
                out[(size_t)BATCH*TOPK + (size_t)row*TOPK + (kk-1)] = (float)bi;
            }
        }
    }
}

extern "C" void kernel_launch(void* const* d_in, const int* in_sizes, int n_in,
                              void* d_out, int out_size, void* d_ws, size_t ws_size,
                              hipStream_t stream) {
    const int*   wordid = (const int*)d_in[0];
    const float* weight = (const float*)d_in[1];
    float* out = (float*)d_out;

    const size_t SZ_B = (size_t)NCB_B * NKB * 64 * 16;   // 64,225,280 B
    const size_t SZ_A = (size_t)NCB_A * NKB * 64 * 16;   //    655,360 B
    // cand: 1024 * 3136 * 4 = 12,845,056 B ; total 77,725,696 B (== round-4 footprint, fits)

    char* p = (char*)d_ws;
    ushort*   ws_b = (ushort*)p;  p += SZ_B;
    ushort*   ws_a = (ushort*)p;  p += SZ_A;
    unsigned* cand = (unsigned*)p;

    convert_frags<<<NCB_B + NCB_A, 256, 0, stream>>>(wordid, weight, ws_b, ws_a, NCB_B);
    sim_gemm<<<dim3(NCHUNK, 8), 256, 0, stream>>>(ws_a, ws_b, cand);
    merge_rescore<<<BATCH, 64, 0, stream>>>(cand, wordid, weight, out);
}